// Round 9
// baseline (539.000 us; speedup 1.0000x reference)
//
#include <hip/hip_runtime.h>
#include <hip/hip_cooperative_groups.h>
#include <math.h>

namespace cg = cooperative_groups;

#define B_   32
#define N_   1024
#define C_   4096
#define HC_  2048
#define D_   64
#define NT_  32768           // B*N tokens
#define KS_  4               // K splits for the P-GEMM
#define KC_  (HC_ / KS_)     // 512 columns per split
#define BKC_ 32              // K-chunk per staging step

__device__ __forceinline__ float4 ld4(const float* p) {
    return *reinterpret_cast<const float4*>(p);
}

// ===========================================================================
// Phase bodies (shared by mega and the fallback kernels)
// ===========================================================================

// ---- P0: GEMM tile (256 rows x 64 d x KC cols) + lower-half stats ---------
__device__ __forceinline__ void p0_gemm_tile(
        int tileId, int t, float* As, float* Bsm,
        const float* __restrict__ x, const float* __restrict__ lnw,
        const float* __restrict__ w1, float* __restrict__ Pp,
        float* __restrict__ spq) {
    const int mt = tileId & 127;   // M tile (256 rows)
    const int ks = tileId >> 7;    // K split (0..3)
    const int T0 = mt * 256;
    const int kbase = ks * KC_;
    const int rt = t & 63;         // row tile: rows rt*4 .. rt*4+3
    const int dt = t >> 6;         // d tile: cols dt*16 .. dt*16+15
    const int lrow = t >> 3;       // loader row (0..31, +32p)
    const int lq = t & 7;          // loader k-quad

    float acc[64];
#pragma unroll
    for (int i = 0; i < 64; ++i) acc[i] = 0.f;
    float sRow[8], qRow[8];
#pragma unroll
    for (int p = 0; p < 8; ++p) { sRow[p] = 0.f; qRow[p] = 0.f; }

    float4 xv[8];
    float4 wv1, wv2;
    float lw1, lw2;
    {   // prologue: load chunk 0
        const int k0 = kbase;
#pragma unroll
        for (int p = 0; p < 8; ++p)
            xv[p] = ld4(x + (size_t)(T0 + lrow + 32 * p) * C_ + k0 + lq * 4);
        const float4* s4 = reinterpret_cast<const float4*>(
            w1 + (size_t)k0 * D_);
        wv1 = s4[t]; wv2 = s4[256 + t];
        lw1 = lnw[k0 + (t >> 4)];
        lw2 = lnw[k0 + 16 + (t >> 4)];
    }

#pragma unroll 1
    for (int kc = 0; kc < KC_ / BKC_; ++kc) {
#pragma unroll
        for (int p = 0; p < 8; ++p) {
            const float4 v = xv[p];
            const int r = lrow + 32 * p;
            const int g = r >> 2, rm = r & 3;
            const int kb = 4 * lq;
            As[(kb + 0) * 256 + (((g ^ ((kb + 0) & 7)) << 2) + rm)] = v.x;
            As[(kb + 1) * 256 + (((g ^ ((kb + 1) & 7)) << 2) + rm)] = v.y;
            As[(kb + 2) * 256 + (((g ^ ((kb + 2) & 7)) << 2) + rm)] = v.z;
            As[(kb + 3) * 256 + (((g ^ ((kb + 3) & 7)) << 2) + rm)] = v.w;
            sRow[p] += (v.x + v.y) + (v.z + v.w);
            qRow[p] = fmaf(v.x, v.x, fmaf(v.y, v.y,
                      fmaf(v.z, v.z, fmaf(v.w, v.w, qRow[p]))));
        }
        {
            float4 v1 = wv1, v2 = wv2;
            v1.x *= lw1; v1.y *= lw1; v1.z *= lw1; v1.w *= lw1;
            v2.x *= lw2; v2.y *= lw2; v2.z *= lw2; v2.w *= lw2;
            float4* b4 = reinterpret_cast<float4*>(Bsm);
            b4[t] = v1;
            b4[256 + t] = v2;
        }
        __syncthreads();
        if (kc + 1 < KC_ / BKC_) {
            const int k1 = kbase + (kc + 1) * BKC_;
#pragma unroll
            for (int p = 0; p < 8; ++p)
                xv[p] = ld4(x + (size_t)(T0 + lrow + 32 * p) * C_
                            + k1 + lq * 4);
            const float4* s4 = reinterpret_cast<const float4*>(
                w1 + (size_t)k1 * D_);
            wv1 = s4[t]; wv2 = s4[256 + t];
            lw1 = lnw[k1 + (t >> 4)];
            lw2 = lnw[k1 + 16 + (t >> 4)];
        }
#pragma unroll 4
        for (int k = 0; k < BKC_; ++k) {
            const float4 a4 = *reinterpret_cast<const float4*>(
                As + k * 256 + ((rt ^ (k & 7)) << 2));
            const float* br = Bsm + k * D_ + dt * 16;
            const float4 b0 = ld4(br), b1v = ld4(br + 4),
                         b2v = ld4(br + 8), b3v = ld4(br + 12);
            const float av[4] = {a4.x, a4.y, a4.z, a4.w};
            const float bv[16] = {b0.x, b0.y, b0.z, b0.w,
                                  b1v.x, b1v.y, b1v.z, b1v.w,
                                  b2v.x, b2v.y, b2v.z, b2v.w,
                                  b3v.x, b3v.y, b3v.z, b3v.w};
#pragma unroll
            for (int ri = 0; ri < 4; ++ri)
#pragma unroll
                for (int cj = 0; cj < 16; ++cj)
                    acc[ri * 16 + cj] =
                        fmaf(av[ri], bv[cj], acc[ri * 16 + cj]);
        }
        __syncthreads();
    }
#pragma unroll
    for (int ri = 0; ri < 4; ++ri) {
        float* dst = Pp + ((size_t)ks * NT_ + T0 + rt * 4 + ri) * D_ + dt * 16;
#pragma unroll
        for (int c = 0; c < 4; ++c)
            *reinterpret_cast<float4*>(dst + c * 4) = make_float4(
                acc[ri * 16 + c * 4], acc[ri * 16 + c * 4 + 1],
                acc[ri * 16 + c * 4 + 2], acc[ri * 16 + c * 4 + 3]);
    }
#pragma unroll
    for (int p = 0; p < 8; ++p) {
        float s = sRow[p], q = qRow[p];
        s += __shfl_xor(s, 1); q += __shfl_xor(q, 1);
        s += __shfl_xor(s, 2); q += __shfl_xor(q, 2);
        s += __shfl_xor(s, 4); q += __shfl_xor(q, 4);
        if (lq == 0) {
            const size_t r = (size_t)(T0 + lrow + 32 * p) * 8;
            spq[r + ks] = s;
            spq[r + 4 + ks] = q;
        }
    }
}

// ---- P1: upper stats + g-accum for one 64-row group -----------------------
__device__ __forceinline__ void p1_upper_group(
        int u, int t, float* As /* 32KB scratch */,
        const float* __restrict__ x, const float* __restrict__ lnw,
        const float* __restrict__ lnb, const float* __restrict__ spq,
        float* __restrict__ muv, float* __restrict__ rsv,
        float* __restrict__ part) {
    const int lane = t & 63, w = t >> 6;
    const int b = u >> 4;          // batch
    const int g = u & 15;          // 64-row group
    float4 wv[8], bv[8], gacc[8];
#pragma unroll
    for (int m = 0; m < 8; ++m) {
        wv[m] = ld4(lnw + HC_ + (m * 64 + lane) * 4);
        bv[m] = ld4(lnb + HC_ + (m * 64 + lane) * 4);
        gacc[m] = make_float4(0.f, 0.f, 0.f, 0.f);
    }
    for (int i = 0; i < 16; ++i) {
        const int tok = b * N_ + g * 64 + w * 16 + i;
        const float* row = x + (size_t)tok * C_ + HC_;
        float4 v[8];
        float s = 0.f, q = 0.f;
#pragma unroll
        for (int m = 0; m < 8; ++m) {
            v[m] = ld4(row + (m * 64 + lane) * 4);
            s += (v[m].x + v[m].y) + (v[m].z + v[m].w);
            q = fmaf(v[m].x, v[m].x, fmaf(v[m].y, v[m].y,
                fmaf(v[m].z, v[m].z, fmaf(v[m].w, v[m].w, q))));
        }
#pragma unroll
        for (int o = 1; o < 64; o <<= 1) {
            s += __shfl_xor(s, o);
            q += __shfl_xor(q, o);
        }
        const float4 s0 = ld4(spq + (size_t)tok * 8);
        const float4 q0 = ld4(spq + (size_t)tok * 8 + 4);
        const float S = s + (s0.x + s0.y) + (s0.z + s0.w);
        const float Q = q + (q0.x + q0.y) + (q0.z + q0.w);
        const float mu = S * (1.f / C_);
        const float rs = rsqrtf(Q * (1.f / C_) - mu * mu + 1e-5f);
        if (lane == 0) {
            muv[tok] = mu;
            rsv[tok] = rs;
        }
#pragma unroll
        for (int m = 0; m < 8; ++m) {
            gacc[m].x += (v[m].x - mu) * rs * wv[m].x + bv[m].x;
            gacc[m].y += (v[m].y - mu) * rs * wv[m].y + bv[m].y;
            gacc[m].z += (v[m].z - mu) * rs * wv[m].z + bv[m].z;
            gacc[m].w += (v[m].w - mu) * rs * wv[m].w + bv[m].w;
        }
    }
    float (*sh)[HC_] = reinterpret_cast<float(*)[HC_]>(As);
    __syncthreads();
#pragma unroll
    for (int m = 0; m < 8; ++m)
        *reinterpret_cast<float4*>(&sh[w][(m * 64 + lane) * 4]) = gacc[m];
    __syncthreads();
    float* pp = part + (size_t)u * HC_;
#pragma unroll
    for (int m = 0; m < 8; ++m) {
        const int j = (m * 64 + lane) * 4;
        const float4 a0 = ld4(&sh[0][j]);
        const float4 a1 = ld4(&sh[1][j]);
        const float4 a2 = ld4(&sh[2][j]);
        const float4 a3 = ld4(&sh[3][j]);
        float4 r;
        r.x = (a0.x + a1.x) + (a2.x + a3.x);
        r.y = (a0.y + a1.y) + (a2.y + a3.y);
        r.z = (a0.z + a1.z) + (a2.z + a3.z);
        r.w = (a0.w + a1.w) + (a2.w + a3.w);
        if (w == (m & 3))
            *reinterpret_cast<float4*>(pp + j) = r;
    }
}

// ---- P2: part-reduce + partial GEMV for one job ---------------------------
__device__ __forceinline__ void p2_job(
        int job, int t, float* Gs, float* red, int nPartPerBatch,
        const float* __restrict__ part, const float* __restrict__ w1,
        const float* __restrict__ lnw, const float* __restrict__ lnb,
        float* __restrict__ gpart, float* __restrict__ Wpart,
        float* __restrict__ Bpart) {
    const int d = t & 63, s = t >> 6;
    if (job < 256) {
        const int b = job >> 3, jq = job & 7;
        const int j = jq * 256 + t;
        float a = 0.f;
        for (int k = 0; k < nPartPerBatch; ++k)
            a += part[(size_t)(b * nPartPerBatch + k) * HC_ + j];
        Gs[t] = a;
        __syncthreads();
        float acc = 0.f;
        const int j0 = jq * 256 + s * 64;
        for (int jj = 0; jj < 64; ++jj)
            acc = fmaf(Gs[s * 64 + jj],
                       w1[(size_t)(HC_ + j0 + jj) * D_ + d], acc);
        red[s * 64 + d] = acc;
        __syncthreads();
        if (s == 0)
            gpart[(size_t)job * 64 + d] =
                red[d] + red[64 + d] + red[128 + d] + red[192 + d];
        __syncthreads();
    } else {
        const int wq = job - 256;
        const int c0 = wq * 256 + s * 64;
        float a = 0.f, c2 = 0.f;
        for (int c = c0; c < c0 + 64; ++c) {
            const float wvv = w1[(size_t)c * D_ + d];
            a = fmaf(lnw[c], wvv, a);
            c2 = fmaf(lnb[c], wvv, c2);
        }
        red[s * 64 + d] = a;
        red[256 + s * 64 + d] = c2;
        __syncthreads();
        if (s == 0) {
            Wpart[wq * 64 + d] =
                red[d] + red[64 + d] + red[128 + d] + red[192 + d];
            Bpart[wq * 64 + d] = red[256 + d] + red[320 + d]
                               + red[384 + d] + red[448 + d];
        }
        __syncthreads();
    }
}

// ---- P4: decision + masked copy for one token -----------------------------
__device__ __forceinline__ void p4_token(
        int token, int lane,
        const float* __restrict__ Pp, const float* __restrict__ muv,
        const float* __restrict__ rsv, const float* __restrict__ gterm,
        const float* __restrict__ W1s, const float* __restrict__ Bs,
        const float* __restrict__ b1, const float* __restrict__ w2,
        const float* __restrict__ b2, const float* __restrict__ gum,
        const float* __restrict__ x, float* __restrict__ out) {
    const int b = token >> 10;
    const float2 gv = *reinterpret_cast<const float2*>(gum + token * 2);
    float p = 0.f;
#pragma unroll
    for (int s = 0; s < KS_; ++s)
        p += Pp[((size_t)s * NT_ + token) * D_ + lane];

    const float mu = muv[token], rs = rsv[token];
    float h = rs * (p - mu * W1s[lane]) + Bs[lane] + gterm[b * D_ + lane]
              + b1[lane];
    h = 0.5f * h * (1.f + erff(h * 0.70710678118654752f));
    const float2 w2v = *reinterpret_cast<const float2*>(w2 + lane * 2);
    float l0 = h * w2v.x;
    float l1 = h * w2v.y;
#pragma unroll
    for (int o = 1; o < 64; o <<= 1) {
        l0 += __shfl_xor(l0, o);
        l1 += __shfl_xor(l1, o);
    }
    const float z0 = l0 + b2[0] + gv.x;
    const float z1 = l1 + b2[1] + gv.y;

    float4* dst = reinterpret_cast<float4*>(out + (size_t)token * C_);
    if (z0 >= z1) {
        const float4* src =
            reinterpret_cast<const float4*>(x + (size_t)token * C_);
#pragma unroll
        for (int c = 0; c < 16; ++c)
            dst[c * 64 + lane] = src[c * 64 + lane];
    } else {
        const float4 z = make_float4(0.f, 0.f, 0.f, 0.f);
#pragma unroll
        for (int c = 0; c < 16; ++c)
            dst[c * 64 + lane] = z;
    }
}

// ===========================================================================
// MEGA: all phases in one cooperative kernel, grid-stride (any grid size).
// part layout: 512 rows (one per 64-row group), nPartPerBatch = 16.
// ===========================================================================
__global__ __launch_bounds__(256) void mega(
        const float* __restrict__ x, const float* __restrict__ gum,
        const float* __restrict__ lnw, const float* __restrict__ lnb,
        const float* __restrict__ w1, const float* __restrict__ b1,
        const float* __restrict__ w2, const float* __restrict__ b2,
        float* __restrict__ out, float* __restrict__ Pp,
        float* __restrict__ muv, float* __restrict__ rsv,
        float* __restrict__ part, float* __restrict__ gterm,
        float* __restrict__ W1s, float* __restrict__ Bs,
        float* __restrict__ spq, float* __restrict__ gpart,
        float* __restrict__ Wpart, float* __restrict__ Bpart) {
    __shared__ float As[BKC_ * 256];   // 32 KB
    __shared__ float Bsm[BKC_ * D_];   // 8 KB

    cg::grid_group grid = cg::this_grid();
    const int t = threadIdx.x;
    const int bid = blockIdx.x;
    const int NB = gridDim.x;
    const int lane = t & 63, w = t >> 6;

    for (int tile = bid; tile < 512; tile += NB)
        p0_gemm_tile(tile, t, As, Bsm, x, lnw, w1, Pp, spq);
    grid.sync();

    for (int u = bid; u < 512; u += NB)
        p1_upper_group(u, t, As, x, lnw, lnb, spq, muv, rsv, part);
    grid.sync();

    for (int job = bid; job < 264; job += NB)
        p2_job(job, t, Bsm, Bsm + 256, 16, part, w1, lnw, lnb,
               gpart, Wpart, Bpart);
    grid.sync();

    for (int j = bid; j < 33; j += NB) {
        if (j < B_ && t < 64) {
            float a = 0.f;
#pragma unroll
            for (int q = 0; q < 8; ++q)
                a += gpart[(size_t)(j * 8 + q) * 64 + t];
            gterm[j * D_ + t] = a * (1.f / N_);
        } else if (j == B_ && t < 64) {
            float a = 0.f, c2 = 0.f;
#pragma unroll
            for (int q = 0; q < 8; ++q) {
                a += Wpart[q * 64 + t];
                c2 += Bpart[q * 64 + t];
            }
            W1s[t] = a;
            Bs[t] = c2;
        }
    }
    grid.sync();

    for (int u = bid; u < 512; u += NB)
        for (int i = 0; i < 16; ++i)
            p4_token(u * 64 + w * 16 + i, lane, Pp, muv, rsv, gterm,
                     W1s, Bs, b1, w2, b2, gum, x, out);
}

// ===========================================================================
// Fallback kernels (round-7 proven path; part uses 1024 rows, 32/batch)
// ===========================================================================
__global__ __launch_bounds__(256) void k3_fused(
        const float* __restrict__ x, const float* __restrict__ lnw,
        const float* __restrict__ w1, float* __restrict__ Pp,
        float* __restrict__ spq) {
    __shared__ float As[BKC_ * 256];
    __shared__ float Bsm[BKC_ * D_];
    p0_gemm_tile(blockIdx.x, threadIdx.x, As, Bsm, x, lnw, w1, Pp, spq);
}

__global__ __launch_bounds__(256) void k1_upper(
        const float* __restrict__ x, const float* __restrict__ lnw,
        const float* __restrict__ lnb, const float* __restrict__ spq,
        float* __restrict__ muv, float* __restrict__ rsv,
        float* __restrict__ part) {
    __shared__ float As[BKC_ * 256];
    p1_upper_group(blockIdx.x, threadIdx.x, As, x, lnw, lnb, spq,
                   muv, rsv, part);
}

__global__ __launch_bounds__(256) void k2a_part(
        const float* __restrict__ part, const float* __restrict__ w1,
        const float* __restrict__ lnw, const float* __restrict__ lnb,
        float* __restrict__ gpart, float* __restrict__ Wpart,
        float* __restrict__ Bpart) {
    __shared__ float Gs[256];
    __shared__ float red[512];
    p2_job(blockIdx.x, threadIdx.x, Gs, red, 16, part, w1, lnw, lnb,
           gpart, Wpart, Bpart);
}

__global__ __launch_bounds__(64) void k2b_final(
        const float* __restrict__ gpart, const float* __restrict__ Wpart,
        const float* __restrict__ Bpart, float* __restrict__ gterm,
        float* __restrict__ W1s, float* __restrict__ Bs) {
    const int d = threadIdx.x;
    const int b = blockIdx.x;
    if (b < B_) {
        float a = 0.f;
#pragma unroll
        for (int q = 0; q < 8; ++q)
            a += gpart[(size_t)(b * 8 + q) * 64 + d];
        gterm[b * D_ + d] = a * (1.f / N_);
    } else {
        float a = 0.f, c2 = 0.f;
#pragma unroll
        for (int q = 0; q < 8; ++q) {
            a += Wpart[q * 64 + d];
            c2 += Bpart[q * 64 + d];
        }
        W1s[d] = a;
        Bs[d] = c2;
    }
}

__global__ __launch_bounds__(256) void k45_decide_mask(
        const float* __restrict__ Pp, const float* __restrict__ muv,
        const float* __restrict__ rsv, const float* __restrict__ gterm,
        const float* __restrict__ W1s, const float* __restrict__ Bs,
        const float* __restrict__ b1, const float* __restrict__ w2,
        const float* __restrict__ b2, const float* __restrict__ gum,
        const float* __restrict__ x, float* __restrict__ out) {
    const int lane = threadIdx.x & 63, w = threadIdx.x >> 6;
    p4_token(blockIdx.x * 4 + w, lane, Pp, muv, rsv, gterm, W1s, Bs,
             b1, w2, b2, gum, x, out);
}

// ===========================================================================
extern "C" void kernel_launch(void* const* d_in, const int* in_sizes, int n_in,
                              void* d_out, int out_size, void* d_ws,
                              size_t ws_size, hipStream_t stream) {
    const float* x   = (const float*)d_in[0];
    const float* gum = (const float*)d_in[1];
    const float* lnw = (const float*)d_in[2];
    const float* lnb = (const float*)d_in[3];
    const float* w1  = (const float*)d_in[4];
    const float* b1  = (const float*)d_in[5];
    const float* w2  = (const float*)d_in[6];
    const float* b2  = (const float*)d_in[7];
    float* out = (float*)d_out;

    float* wsf   = (float*)d_ws;
    float* Pp    = wsf;                                   // 4*32768*64
    float* muv   = Pp + (size_t)KS_ * NT_ * D_;           // 32768
    float* rsv   = muv + NT_;                             // 32768
    float* part  = rsv + NT_;                             // 512*2048
    float* gterm = part + (size_t)512 * HC_;              // 32*64
    float* W1s   = gterm + B_ * D_;                       // 64
    float* Bs    = W1s + D_;                              // 64
    float* spq   = Bs + D_;                               // 32768*8
    float* gpart = spq + (size_t)NT_ * 8;                 // 256*64
    float* Wpart = gpart + 256 * 64;                      // 8*64
    float* Bpart = Wpart + 8 * 64;                        // 8*64

    // --- try cooperative mega (gated; fall back on any failure) ---
    int dev = 0;
    (void)hipGetDevice(&dev);
    int coop = 0, numCU = 0;
    (void)hipDeviceGetAttribute(&coop, hipDeviceAttributeCooperativeLaunch,
                                dev);
    (void)hipDeviceGetAttribute(&numCU,
                                hipDeviceAttributeMultiprocessorCount, dev);
    if (coop && numCU > 0) {
        int maxBlk = 0;
        hipError_t oe = hipOccupancyMaxActiveBlocksPerMultiprocessor(
            &maxBlk, (const void*)mega, 256, 0);
        if (oe == hipSuccess && maxBlk >= 1) {
            int gridSz = maxBlk * numCU;
            if (gridSz > 512) gridSz = 512;
            void* args[] = {
                (void*)&x, (void*)&gum, (void*)&lnw, (void*)&lnb,
                (void*)&w1, (void*)&b1, (void*)&w2, (void*)&b2,
                (void*)&out, (void*)&Pp, (void*)&muv, (void*)&rsv,
                (void*)&part, (void*)&gterm, (void*)&W1s, (void*)&Bs,
                (void*)&spq, (void*)&gpart, (void*)&Wpart, (void*)&Bpart};
            hipError_t le = hipLaunchCooperativeKernel(
                (void*)mega, dim3(gridSz), dim3(256), args, 0, stream);
            if (le == hipSuccess) return;
            (void)hipGetLastError();   // clear sticky error, fall through
        } else {
            (void)hipGetLastError();
        }
    }

    // --- fallback: proven five-kernel path ---
    k3_fused<<<KS_ * 128, 256, 0, stream>>>(x, lnw, w1, Pp, spq);
    k1_upper<<<512, 256, 0, stream>>>(x, lnw, lnb, spq, muv, rsv, part);
    k2a_part<<<264, 256, 0, stream>>>(part, w1, lnw, lnb,
                                      gpart, Wpart, Bpart);
    k2b_final<<<33, 64, 0, stream>>>(gpart, Wpart, Bpart, gterm, W1s, Bs);
    k45_decide_mask<<<NT_ / 4, 256, 0, stream>>>(Pp, muv, rsv, gterm, W1s,
                                                 Bs, b1, w2, b2, gum, x, out);
}

// Round 10
// 398.063 us; speedup vs baseline: 1.3541x; 1.3541x over previous
//
#include <hip/hip_runtime.h>
#include <math.h>

#define B_   32
#define N_   1024
#define C_   4096
#define HC_  2048
#define D_   64
#define NT_  32768           // B*N tokens
#define KS_  4               // K splits for the P-GEMM
#define KC_  (HC_ / KS_)     // 512 columns per split
#define BKC_ 32              // K-chunk per staging step

__device__ __forceinline__ float4 ld4(const float* p) {
    return *reinterpret_cast<const float4*>(p);
}

// ---------------------------------------------------------------------------
// K3f: fused GEMM + lower-half stats.  M128 tiles, 4 blocks/CU.
// P[t,d] = sum_c x[t,c] * (lnw[c]*w1[c,d]).
// Thread tile 4 rows x 8 d (acc[32]).  A staged k-major with 5-bit
// permutation perm5(k) = (5*(k>>2)+(k&3))&31 -> staging writes 2-way (free),
// compute read one b128/k.  grid = KS_*256 = 1024, block 256.
// ---------------------------------------------------------------------------
__global__ __launch_bounds__(256) void k3_fused(
        const float* __restrict__ x, const float* __restrict__ lnw,
        const float* __restrict__ w1, float* __restrict__ Pp,
        float* __restrict__ spq) {
    __shared__ float As[BKC_ * 128];   // 16 KB
    __shared__ float Bsm[BKC_ * D_];   // 8 KB

    const int t = threadIdx.x;
    const int mt = blockIdx.x & 255;   // M tile (128 rows)
    const int ks = blockIdx.x >> 8;    // K split (0..3)
    const int T0 = mt * 128;
    const int kbase = ks * KC_;
    const int rt = t & 31;             // row tile: rows rt*4 .. rt*4+3
    const int dt = t >> 5;             // d tile: cols dt*8 .. dt*8+7
    const int lrow = t >> 3;           // loader row (0..31, +32p)
    const int lq = t & 7;              // loader k-quad

    float acc[32];
#pragma unroll
    for (int i = 0; i < 32; ++i) acc[i] = 0.f;
    float sRow[4], qRow[4];
#pragma unroll
    for (int p = 0; p < 4; ++p) { sRow[p] = 0.f; qRow[p] = 0.f; }

    float4 xv[4];
    float4 wv1, wv2;
    float lw1, lw2;
    {   // prologue: load chunk 0
        const int k0 = kbase;
#pragma unroll
        for (int p = 0; p < 4; ++p)
            xv[p] = ld4(x + (size_t)(T0 + lrow + 32 * p) * C_ + k0 + lq * 4);
        const float4* s4 = reinterpret_cast<const float4*>(
            w1 + (size_t)k0 * D_);
        wv1 = s4[t]; wv2 = s4[256 + t];
        lw1 = lnw[k0 + (t >> 4)];
        lw2 = lnw[k0 + 16 + (t >> 4)];
    }

#pragma unroll 1
    for (int kc = 0; kc < KC_ / BKC_; ++kc) {
        // --- stage A (perm5) + stats from regs ---
#pragma unroll
        for (int p = 0; p < 4; ++p) {
            const float4 v = xv[p];
            const int r = lrow + 32 * p;
            const int gq = r >> 2, rm = r & 3;
            const int kb = 4 * lq;
#pragma unroll
            for (int j = 0; j < 4; ++j) {
                const float c = (j == 0) ? v.x : (j == 1) ? v.y
                              : (j == 2) ? v.z : v.w;
                const int p5 = (5 * lq + j) & 31;
                As[(kb + j) * 128 + (((gq ^ p5) << 2) + rm)] = c;
            }
            sRow[p] += (v.x + v.y) + (v.z + v.w);
            qRow[p] = fmaf(v.x, v.x, fmaf(v.y, v.y,
                      fmaf(v.z, v.z, fmaf(v.w, v.w, qRow[p]))));
        }
        // --- stage B (lnw-folded) ---
        {
            float4 v1 = wv1, v2 = wv2;
            v1.x *= lw1; v1.y *= lw1; v1.z *= lw1; v1.w *= lw1;
            v2.x *= lw2; v2.y *= lw2; v2.z *= lw2; v2.w *= lw2;
            float4* b4 = reinterpret_cast<float4*>(Bsm);
            b4[t] = v1;
            b4[256 + t] = v2;
        }
        __syncthreads();
        // --- prefetch next chunk (overlaps FMA loop) ---
        if (kc + 1 < KC_ / BKC_) {
            const int k1 = kbase + (kc + 1) * BKC_;
#pragma unroll
            for (int p = 0; p < 4; ++p)
                xv[p] = ld4(x + (size_t)(T0 + lrow + 32 * p) * C_
                            + k1 + lq * 4);
            const float4* s4 = reinterpret_cast<const float4*>(
                w1 + (size_t)k1 * D_);
            wv1 = s4[t]; wv2 = s4[256 + t];
            lw1 = lnw[k1 + (t >> 4)];
            lw2 = lnw[k1 + 16 + (t >> 4)];
        }
        // --- FMA loop ---
#pragma unroll 8
        for (int k = 0; k < BKC_; ++k) {
            const int p5 = (5 * (k >> 2) + (k & 3)) & 31;
            const float4 a4 = *reinterpret_cast<const float4*>(
                As + k * 128 + ((rt ^ p5) << 2));
            const float* br = Bsm + k * D_ + dt * 8;
            const float4 b0 = ld4(br), b1v = ld4(br + 4);
            const float av[4] = {a4.x, a4.y, a4.z, a4.w};
            const float bv[8] = {b0.x, b0.y, b0.z, b0.w,
                                 b1v.x, b1v.y, b1v.z, b1v.w};
#pragma unroll
            for (int ri = 0; ri < 4; ++ri)
#pragma unroll
                for (int cj = 0; cj < 8; ++cj)
                    acc[ri * 8 + cj] =
                        fmaf(av[ri], bv[cj], acc[ri * 8 + cj]);
        }
        __syncthreads();
    }
    // --- write P: row rt*4+ri, cols dt*8 .. +7 ---
#pragma unroll
    for (int ri = 0; ri < 4; ++ri) {
        float* dst = Pp + ((size_t)ks * NT_ + T0 + rt * 4 + ri) * D_ + dt * 8;
        *reinterpret_cast<float4*>(dst) = make_float4(
            acc[ri * 8 + 0], acc[ri * 8 + 1], acc[ri * 8 + 2],
            acc[ri * 8 + 3]);
        *reinterpret_cast<float4*>(dst + 4) = make_float4(
            acc[ri * 8 + 4], acc[ri * 8 + 5], acc[ri * 8 + 6],
            acc[ri * 8 + 7]);
    }
    // --- reduce + write stats ---
#pragma unroll
    for (int p = 0; p < 4; ++p) {
        float s = sRow[p], q = qRow[p];
        s += __shfl_xor(s, 1); q += __shfl_xor(q, 1);
        s += __shfl_xor(s, 2); q += __shfl_xor(q, 2);
        s += __shfl_xor(s, 4); q += __shfl_xor(q, 4);
        if (lq == 0) {
            const size_t r = (size_t)(T0 + lrow + 32 * p) * 8;
            spq[r + ks] = s;
            spq[r + 4 + ks] = q;
        }
    }
}

// ---------------------------------------------------------------------------
// K1u: upper-half stats + g-accum.  1024 blocks x 32 rows (4 blocks/CU).
// Each wave owns 8 rows; lane owns 32 upper cols.  Stats via xor-butterfly;
// one barrier for the cross-wave gacc reduce.  part: 1024 rows.
// ---------------------------------------------------------------------------
__global__ __launch_bounds__(256) void k1_upper(
        const float* __restrict__ x, const float* __restrict__ lnw,
        const float* __restrict__ lnb, const float* __restrict__ spq,
        float* __restrict__ muv, float* __restrict__ rsv,
        float* __restrict__ part) {
    __shared__ float sh[4][HC_];     // 32 KB
    const int t = threadIdx.x;
    const int lane = t & 63, w = t >> 6;
    const int bid = blockIdx.x;
    const int b = bid >> 5;          // batch
    const int g = bid & 31;          // 32-row group

    float4 wv[8], bv[8], gacc[8];
#pragma unroll
    for (int m = 0; m < 8; ++m) {
        wv[m] = ld4(lnw + HC_ + (m * 64 + lane) * 4);
        bv[m] = ld4(lnb + HC_ + (m * 64 + lane) * 4);
        gacc[m] = make_float4(0.f, 0.f, 0.f, 0.f);
    }

    for (int i = 0; i < 8; ++i) {
        const int tok = b * N_ + g * 32 + w * 8 + i;
        const float* row = x + (size_t)tok * C_ + HC_;
        float4 v[8];
        float s = 0.f, q = 0.f;
#pragma unroll
        for (int m = 0; m < 8; ++m) {
            v[m] = ld4(row + (m * 64 + lane) * 4);
            s += (v[m].x + v[m].y) + (v[m].z + v[m].w);
            q = fmaf(v[m].x, v[m].x, fmaf(v[m].y, v[m].y,
                fmaf(v[m].z, v[m].z, fmaf(v[m].w, v[m].w, q))));
        }
#pragma unroll
        for (int o = 1; o < 64; o <<= 1) {
            s += __shfl_xor(s, o);
            q += __shfl_xor(q, o);
        }
        const float4 s0 = ld4(spq + (size_t)tok * 8);
        const float4 q0 = ld4(spq + (size_t)tok * 8 + 4);
        const float S = s + (s0.x + s0.y) + (s0.z + s0.w);
        const float Q = q + (q0.x + q0.y) + (q0.z + q0.w);
        const float mu = S * (1.f / C_);
        const float rs = rsqrtf(Q * (1.f / C_) - mu * mu + 1e-5f);
        if (lane == 0) {
            muv[tok] = mu;
            rsv[tok] = rs;
        }
#pragma unroll
        for (int m = 0; m < 8; ++m) {
            gacc[m].x += (v[m].x - mu) * rs * wv[m].x + bv[m].x;
            gacc[m].y += (v[m].y - mu) * rs * wv[m].y + bv[m].y;
            gacc[m].z += (v[m].z - mu) * rs * wv[m].z + bv[m].z;
            gacc[m].w += (v[m].w - mu) * rs * wv[m].w + bv[m].w;
        }
    }
    // cross-wave reduction: 4 wave-partials -> 1 block partial
#pragma unroll
    for (int m = 0; m < 8; ++m)
        *reinterpret_cast<float4*>(&sh[w][(m * 64 + lane) * 4]) = gacc[m];
    __syncthreads();
    float* pp = part + (size_t)bid * HC_;
#pragma unroll
    for (int m = 0; m < 8; ++m) {
        const int j = (m * 64 + lane) * 4;
        const float4 a0 = ld4(&sh[0][j]);
        const float4 a1 = ld4(&sh[1][j]);
        const float4 a2 = ld4(&sh[2][j]);
        const float4 a3 = ld4(&sh[3][j]);
        float4 r;
        r.x = (a0.x + a1.x) + (a2.x + a3.x);
        r.y = (a0.y + a1.y) + (a2.y + a3.y);
        r.z = (a0.z + a1.z) + (a2.z + a3.z);
        r.w = (a0.w + a1.w) + (a2.w + a3.w);
        if (w == (m & 3))    // spread the 8 stores across the 4 waves
            *reinterpret_cast<float4*>(pp + j) = r;
    }
}

// ---------------------------------------------------------------------------
// K2a: fold partial-reduce + partial GEMVs.  grid 264, block 256.
// blocks 0..255: (b, jq) — sum 32 partials for j-range, then GEMV.
// blocks 256..263: Wpart/Bpart over 256 c each.
// ---------------------------------------------------------------------------
__global__ __launch_bounds__(256) void k2a_part(
        const float* __restrict__ part, const float* __restrict__ w1,
        const float* __restrict__ lnw, const float* __restrict__ lnb,
        float* __restrict__ gpart, float* __restrict__ Wpart,
        float* __restrict__ Bpart) {
    __shared__ float Gs[256];
    __shared__ float red[512];
    const int t = threadIdx.x;
    const int d = t & 63, s = t >> 6;
    const int blk = blockIdx.x;
    if (blk < 256) {
        const int b = blk >> 3, jq = blk & 7;
        const int j = jq * 256 + t;
        float a = 0.f;
        for (int k = 0; k < 32; ++k)
            a += part[(size_t)(b * 32 + k) * HC_ + j];
        Gs[t] = a;
        __syncthreads();
        float acc = 0.f;
        const int j0 = jq * 256 + s * 64;
        for (int jj = 0; jj < 64; ++jj)
            acc = fmaf(Gs[s * 64 + jj],
                       w1[(size_t)(HC_ + j0 + jj) * D_ + d], acc);
        red[s * 64 + d] = acc;
        __syncthreads();
        if (s == 0)
            gpart[(size_t)blk * 64 + d] =
                red[d] + red[64 + d] + red[128 + d] + red[192 + d];
    } else {
        const int wq = blk - 256;
        const int c0 = wq * 256 + s * 64;
        float a = 0.f, c2 = 0.f;
        for (int c = c0; c < c0 + 64; ++c) {
            const float wvv = w1[(size_t)c * D_ + d];
            a = fmaf(lnw[c], wvv, a);
            c2 = fmaf(lnb[c], wvv, c2);
        }
        red[s * 64 + d] = a;
        red[256 + s * 64 + d] = c2;
        __syncthreads();
        if (s == 0) {
            Wpart[wq * 64 + d] =
                red[d] + red[64 + d] + red[128 + d] + red[192 + d];
            Bpart[wq * 64 + d] = red[256 + d] + red[320 + d]
                               + red[384 + d] + red[448 + d];
        }
    }
}

// ---------------------------------------------------------------------------
// K2b: final reduce.  grid 33, block 64.
// ---------------------------------------------------------------------------
__global__ __launch_bounds__(64) void k2b_final(
        const float* __restrict__ gpart, const float* __restrict__ Wpart,
        const float* __restrict__ Bpart, float* __restrict__ gterm,
        float* __restrict__ W1s, float* __restrict__ Bs) {
    const int d = threadIdx.x;
    const int b = blockIdx.x;
    if (b < B_) {
        float a = 0.f;
#pragma unroll
        for (int q = 0; q < 8; ++q)
            a += gpart[(size_t)(b * 8 + q) * 64 + d];
        gterm[b * D_ + d] = a * (1.f / N_);
    } else {
        float a = 0.f, c2 = 0.f;
#pragma unroll
        for (int q = 0; q < 8; ++q) {
            a += Wpart[q * 64 + d];
            c2 += Bpart[q * 64 + d];
        }
        W1s[d] = a;
        Bs[d] = c2;
    }
}

// ---------------------------------------------------------------------------
// K45: per-token decision + masked copy, one wave per token (barrier-free).
// Dropped tokens write zeros WITHOUT reading x.  grid 8192, block 256.
// ---------------------------------------------------------------------------
__global__ __launch_bounds__(256) void k45_decide_mask(
        const float* __restrict__ Pp, const float* __restrict__ muv,
        const float* __restrict__ rsv, const float* __restrict__ gterm,
        const float* __restrict__ W1s, const float* __restrict__ Bs,
        const float* __restrict__ b1, const float* __restrict__ w2,
        const float* __restrict__ b2, const float* __restrict__ gum,
        const float* __restrict__ x, float* __restrict__ out) {
    const int t = threadIdx.x;
    const int lane = t & 63, w = t >> 6;
    const int token = blockIdx.x * 4 + w;
    const int b = token >> 10;

    const float2 gv = *reinterpret_cast<const float2*>(gum + token * 2);
    float p = 0.f;
#pragma unroll
    for (int s = 0; s < KS_; ++s)
        p += Pp[((size_t)s * NT_ + token) * D_ + lane];

    const float mu = muv[token], rs = rsv[token];
    float h = rs * (p - mu * W1s[lane]) + Bs[lane] + gterm[b * D_ + lane]
              + b1[lane];
    h = 0.5f * h * (1.f + erff(h * 0.70710678118654752f));   // exact gelu
    const float2 w2v = *reinterpret_cast<const float2*>(w2 + lane * 2);
    float l0 = h * w2v.x;
    float l1 = h * w2v.y;
#pragma unroll
    for (int o = 1; o < 64; o <<= 1) {
        l0 += __shfl_xor(l0, o);
        l1 += __shfl_xor(l1, o);
    }
    const float z0 = l0 + b2[0] + gv.x;
    const float z1 = l1 + b2[1] + gv.y;

    float4* dst = reinterpret_cast<float4*>(out + (size_t)token * C_);
    if (z0 >= z1) {    // keep (argmax ties -> index 0): copy x
        const float4* src =
            reinterpret_cast<const float4*>(x + (size_t)token * C_);
#pragma unroll
        for (int c = 0; c < 16; ++c)
            dst[c * 64 + lane] = src[c * 64 + lane];
    } else {           // drop: write zeros, skip the x read
        const float4 z = make_float4(0.f, 0.f, 0.f, 0.f);
#pragma unroll
        for (int c = 0; c < 16; ++c)
            dst[c * 64 + lane] = z;
    }
}

// ---------------------------------------------------------------------------
extern "C" void kernel_launch(void* const* d_in, const int* in_sizes, int n_in,
                              void* d_out, int out_size, void* d_ws,
                              size_t ws_size, hipStream_t stream) {
    const float* x   = (const float*)d_in[0];
    const float* gum = (const float*)d_in[1];
    const float* lnw = (const float*)d_in[2];
    const float* lnb = (const float*)d_in[3];
    const float* w1  = (const float*)d_in[4];
    const float* b1  = (const float*)d_in[5];
    const float* w2  = (const float*)d_in[6];
    const float* b2  = (const float*)d_in[7];
    float* out = (float*)d_out;

    float* wsf   = (float*)d_ws;
    float* Pp    = wsf;                                   // 4*32768*64
    float* muv   = Pp + (size_t)KS_ * NT_ * D_;           // 32768
    float* rsv   = muv + NT_;                             // 32768
    float* part  = rsv + NT_;                             // 1024*2048
    float* gterm = part + (size_t)1024 * HC_;             // 32*64
    float* W1s   = gterm + B_ * D_;                       // 64
    float* Bs    = W1s + D_;                              // 64
    float* spq   = Bs + D_;                               // 32768*8
    float* gpart = spq + (size_t)NT_ * 8;                 // 256*64
    float* Wpart = gpart + 256 * 64;                      // 8*64
    float* Bpart = Wpart + 8 * 64;                        // 8*64

    k3_fused<<<KS_ * 256, 256, 0, stream>>>(x, lnw, w1, Pp, spq);
    k1_upper<<<1024, 256, 0, stream>>>(x, lnw, lnb, spq, muv, rsv, part);
    k2a_part<<<264, 256, 0, stream>>>(part, w1, lnw, lnb,
                                      gpart, Wpart, Bpart);
    k2b_final<<<33, 64, 0, stream>>>(gpart, Wpart, Bpart, gterm, W1s, Bs);
    k45_decide_mask<<<NT_ / 4, 256, 0, stream>>>(Pp, muv, rsv, gterm, W1s,
                                                 Bs, b1, w2, b2, gum, x, out);
}